// Round 1
// baseline (78.207 us; speedup 1.0000x reference)
//
#include <hip/hip_runtime.h>
#include <math.h>

#define NN 4096
#define BB 8
#define NV4 (NN / 4)          // float4 per row
#define ROWS_PER_WAVE 2
#define WAVES_PER_BLOCK 4
#define ROWS_PER_BLOCK (ROWS_PER_WAVE * WAVES_PER_BLOCK)

__global__ __launch_bounds__(256, 2) void attgru_fused_kernel(
    const float* __restrict__ x,   const float* __restrict__ h,
    const float* __restrict__ adj, const float* __restrict__ Whr,
    const float* __restrict__ bhr, const float* __restrict__ Whz,
    const float* __restrict__ bhz, const float* __restrict__ Whn,
    const float* __restrict__ bhn, float* __restrict__ out)
{
    const int lane = threadIdx.x & 63;
    const int wave = threadIdx.x >> 6;
    const int row0 = blockIdx.x * ROWS_PER_BLOCK + wave * ROWS_PER_WAVE;

    const float4* x4 = reinterpret_cast<const float4*>(x);
    const float4* h4 = reinterpret_cast<const float4*>(h);
    const float4* A0 = reinterpret_cast<const float4*>(adj) + (size_t)row0 * NV4;
    const float4* A1 = A0 + NV4;
    const float4* R0 = reinterpret_cast<const float4*>(Whr) + (size_t)row0 * NV4;
    const float4* R1 = R0 + NV4;
    const float4* Z0 = reinterpret_cast<const float4*>(Whz) + (size_t)row0 * NV4;
    const float4* Z1 = Z0 + NV4;
    const float4* G0 = reinterpret_cast<const float4*>(Whn) + (size_t)row0 * NV4;
    const float4* G1 = G0 + NV4;

    float accA[ROWS_PER_WAVE][BB];
    float accR[ROWS_PER_WAVE][BB];
    float accZ[ROWS_PER_WAVE][BB];
    float accN[ROWS_PER_WAVE][BB];
#pragma unroll
    for (int r = 0; r < ROWS_PER_WAVE; ++r)
#pragma unroll
        for (int b = 0; b < BB; ++b) {
            accA[r][b] = 0.f; accR[r][b] = 0.f; accZ[r][b] = 0.f; accN[r][b] = 0.f;
        }

    // K sweep: 16 chunks of 256 floats (lane l owns 4 consecutive floats)
    for (int c = 0; c < NV4; c += 64) {
        const int idx = c + lane;
        const float4 a0 = A0[idx], a1 = A1[idx];
        const float4 r0 = R0[idx], r1 = R1[idx];
        const float4 z0 = Z0[idx], z1 = Z1[idx];
        const float4 g0 = G0[idx], g1 = G1[idx];
#pragma unroll
        for (int b = 0; b < BB; ++b) {
            const float4 xb = x4[b * NV4 + idx];
            const float4 hb = h4[b * NV4 + idx];
            accA[0][b] += a0.x * xb.x + a0.y * xb.y + a0.z * xb.z + a0.w * xb.w;
            accA[1][b] += a1.x * xb.x + a1.y * xb.y + a1.z * xb.z + a1.w * xb.w;
            accR[0][b] += r0.x * hb.x + r0.y * hb.y + r0.z * hb.z + r0.w * hb.w;
            accR[1][b] += r1.x * hb.x + r1.y * hb.y + r1.z * hb.z + r1.w * hb.w;
            accZ[0][b] += z0.x * hb.x + z0.y * hb.y + z0.z * hb.z + z0.w * hb.w;
            accZ[1][b] += z1.x * hb.x + z1.y * hb.y + z1.z * hb.z + z1.w * hb.w;
            accN[0][b] += g0.x * hb.x + g0.y * hb.y + g0.z * hb.z + g0.w * hb.w;
            accN[1][b] += g1.x * hb.x + g1.y * hb.y + g1.z * hb.z + g1.w * hb.w;
        }
    }

    // Wave butterfly reduction: every lane ends with the full sums.
#pragma unroll
    for (int off = 32; off >= 1; off >>= 1) {
#pragma unroll
        for (int r = 0; r < ROWS_PER_WAVE; ++r)
#pragma unroll
            for (int b = 0; b < BB; ++b) {
                accA[r][b] += __shfl_xor(accA[r][b], off);
                accR[r][b] += __shfl_xor(accR[r][b], off);
                accZ[r][b] += __shfl_xor(accZ[r][b], off);
                accN[r][b] += __shfl_xor(accN[r][b], off);
            }
    }

    // Epilogue: wave-uniform compute, lane 0 stores (16 dwords per wave).
    if (lane == 0) {
#pragma unroll
        for (int r = 0; r < ROWS_PER_WAVE; ++r) {
            const int row = row0 + r;
            const float br = bhr[row], bz = bhz[row], bn = bhn[row];
#pragma unroll
            for (int b = 0; b < BB; ++b) {
                const float agg = accA[r][b];
                const float rg = 1.f / (1.f + __expf(-(agg + accR[r][b] + br)));
                const float zg = 1.f / (1.f + __expf(-(agg + accZ[r][b] + bz)));
                const float ng = tanhf(agg + rg * (accN[r][b] + bn));
                const float hv = h[b * NN + row];
                out[b * NN + row] = (1.f - zg) * ng + zg * hv;
            }
        }
    }
}

extern "C" void kernel_launch(void* const* d_in, const int* in_sizes, int n_in,
                              void* d_out, int out_size, void* d_ws, size_t ws_size,
                              hipStream_t stream) {
    const float* x   = (const float*)d_in[0];
    const float* h   = (const float*)d_in[1];
    const float* adj = (const float*)d_in[2];
    const float* Whr = (const float*)d_in[3];
    const float* bhr = (const float*)d_in[4];
    const float* Whz = (const float*)d_in[5];
    const float* bhz = (const float*)d_in[6];
    const float* Whn = (const float*)d_in[7];
    const float* bhn = (const float*)d_in[8];
    float* out = (float*)d_out;

    const int grid = NN / ROWS_PER_BLOCK;  // 512 blocks
    attgru_fused_kernel<<<grid, 256, 0, stream>>>(x, h, adj, Whr, bhr, Whz, bhz,
                                                  Whn, bhn, out);
}